// Round 1
// baseline (272.461 us; speedup 1.0000x reference)
//
#include <hip/hip_runtime.h>
#include <hip/hip_bf16.h>
#include <hip/hip_fp16.h>

// Problem constants
#define DIMSZ 1024
#define HEADS 16
#define HD 64
#define BATCH 2
#define SEQ 2048
#define MROWS (BATCH*SEQ)   // 4096

typedef _Float16 f16;
typedef _Float16 f16x8 __attribute__((ext_vector_type(8)));
typedef float f32x4 __attribute__((ext_vector_type(4)));

__device__ __forceinline__ void gload_lds16(const void* g, void* l) {
  // 16B direct global->LDS: dest = wave-uniform base + lane*16
  __builtin_amdgcn_global_load_lds(
      (const __attribute__((address_space(1))) unsigned int*)g,
      (__attribute__((address_space(3))) unsigned int*)l, 16, 0, 0);
}

// ---------------- fp32 -> fp16 elementwise (x) ----------------
__global__ __launch_bounds__(256) void k_cvt_x(const float* __restrict__ in,
                                               f16* __restrict__ out) {
  int i = blockIdx.x * 256 + threadIdx.x;   // 4096*1024/4 elems of float4
  float4 v = ((const float4*)in)[i];
  union { f16 h[4]; uint2 u; } p;
  p.h[0] = (f16)v.x; p.h[1] = (f16)v.y; p.h[2] = (f16)v.z; p.h[3] = (f16)v.w;
  ((uint2*)out)[i] = p.u;
}

// ---------------- fp32 [R][C] -> fp16 [C][R] transpose ----------------
__global__ __launch_bounds__(256) void k_tcvt(const float* __restrict__ in,
                                              f16* __restrict__ out,
                                              int R, int C) {
  __shared__ f16 t[64][66];  // +2 pad: 132B row stride -> conflict-free col reads
  int c0 = blockIdx.x * 64, r0 = blockIdx.y * 64;
  int tid = threadIdx.x;
  int cc = tid & 63;
  #pragma unroll
  for (int p = 0; p < 16; p++) {
    int r = p * 4 + (tid >> 6);
    t[r][cc] = (f16)in[(size_t)(r0 + r) * C + c0 + cc];
  }
  __syncthreads();
  int rr = tid & 63;
  #pragma unroll
  for (int p = 0; p < 16; p++) {
    int c = p * 4 + (tid >> 6);
    out[(size_t)(c0 + c) * R + r0 + rr] = t[rr][c];
  }
}

// ---------------- GEMM core (shared shape): C[128x128] tile, BK=64 ----------
// A: [M][1024] fp16 row-major, Bt: [N][1024] fp16 row-major (i.e. B transposed)
// 256 threads = 4 waves in 2x2, each wave 64x64 (4x4 frags of 16x16x32_f16)
#define GEMM_CORE(Aptr, Bptr)                                                  \
  __shared__ __align__(16) f16 As[128 * 64];                                   \
  __shared__ __align__(16) f16 Bs[128 * 64];                                   \
  const int K = 1024;                                                          \
  int tid = threadIdx.x, l = tid & 63, w = tid >> 6;                           \
  int bm = blockIdx.y, bn = blockIdx.x;                                        \
  int wr = (w >> 1) * 64, wc = (w & 1) * 64;                                   \
  const f16* Ag = (Aptr) + (size_t)bm * 128 * K;                               \
  const f16* Bg = (Bptr) + (size_t)bn * 128 * K;                               \
  f32x4 acc[4][4] = {};                                                        \
  for (int kt = 0; kt < K; kt += 64) {                                         \
    __syncthreads();                                                           \
    _Pragma("unroll")                                                          \
    for (int i = 0; i < 4; i++) {                                              \
      int base = i * 256 + w * 64;                                             \
      int chunk = base + l;                                                    \
      int row = chunk >> 3, c = chunk & 7, sc = c ^ (row & 7);                 \
      gload_lds16(Ag + (size_t)row * K + kt + sc * 8, &As[base * 8]);          \
    }                                                                          \
    _Pragma("unroll")                                                          \
    for (int i = 0; i < 4; i++) {                                              \
      int base = i * 256 + w * 64;                                             \
      int chunk = base + l;                                                    \
      int row = chunk >> 3, c = chunk & 7, sc = c ^ (row & 7);                 \
      gload_lds16(Bg + (size_t)row * K + kt + sc * 8, &Bs[base * 8]);          \
    }                                                                          \
    __syncthreads();                                                           \
    f16x8 af[4][2], bf[4][2];                                                  \
    _Pragma("unroll")                                                          \
    for (int m = 0; m < 4; m++)                                                \
      _Pragma("unroll")                                                        \
      for (int kk = 0; kk < 2; kk++) {                                         \
        int row = wr + m * 16 + (l & 15);                                      \
        int pc = (kk * 4 + (l >> 4)) ^ (row & 7);                              \
        af[m][kk] = *(const f16x8*)&As[row * 64 + pc * 8];                     \
      }                                                                        \
    _Pragma("unroll")                                                          \
    for (int n = 0; n < 4; n++)                                                \
      _Pragma("unroll")                                                        \
      for (int kk = 0; kk < 2; kk++) {                                         \
        int row = wc + n * 16 + (l & 15);                                      \
        int pc = (kk * 4 + (l >> 4)) ^ (row & 7);                              \
        bf[n][kk] = *(const f16x8*)&Bs[row * 64 + pc * 8];                     \
      }                                                                        \
    _Pragma("unroll")                                                          \
    for (int m = 0; m < 4; m++)                                                \
      _Pragma("unroll")                                                        \
      for (int n = 0; n < 4; n++)                                              \
        _Pragma("unroll")                                                      \
        for (int kk = 0; kk < 2; kk++)                                         \
          acc[m][n] = __builtin_amdgcn_mfma_f32_16x16x32_f16(af[m][kk],        \
                          bf[n][kk], acc[m][n], 0, 0, 0);                      \
  }

// QKV projection: writes Q,K as [B*H][SEQ][64] fp16, V as [B*H][64][SEQ] fp16
__global__ __launch_bounds__(256) void k_gemm_qkv(
    const f16* __restrict__ A, const f16* __restrict__ Bt,
    const float* __restrict__ bias,
    f16* __restrict__ qb, f16* __restrict__ kb, f16* __restrict__ vb) {
  GEMM_CORE(A, Bt)
  int gm0 = bm * 128 + wr;
  int gn0 = bn * 128 + wc;
  #pragma unroll
  for (int n = 0; n < 4; n++) {
    int col = gn0 + n * 16 + (l & 15);
    float bv = bias[col];
    int which = col >> 10, rest = col & 1023, h = rest >> 6, d = rest & 63;
    #pragma unroll
    for (int m = 0; m < 4; m++) {
      int rowb = gm0 + m * 16 + ((l >> 4) << 2);
      int b = rowb >> 11, nn = rowb & 2047;
      if (which == 2) {
        union { f16 h[4]; uint2 u; } pk;
        #pragma unroll
        for (int j = 0; j < 4; j++) pk.h[j] = (f16)(acc[m][n][j] + bv);
        *(uint2*)(vb + ((size_t)(b * HEADS + h) * 64 + d) * SEQ + nn) = pk.u;
      } else {
        f16* dst = (which ? kb : qb) + ((size_t)(b * HEADS + h) * SEQ + nn) * 64 + d;
        #pragma unroll
        for (int j = 0; j < 4; j++) dst[(size_t)j * 64] = (f16)(acc[m][n][j] + bv);
      }
    }
  }
}

// Output projection: ctx[4096][1024] fp16 @ Wout^T -> fp32 out + bias
__global__ __launch_bounds__(256) void k_gemm_out(
    const f16* __restrict__ A, const f16* __restrict__ Bt,
    const float* __restrict__ bias, float* __restrict__ out) {
  GEMM_CORE(A, Bt)
  int gm0 = bm * 128 + wr;
  int gn0 = bn * 128 + wc;
  #pragma unroll
  for (int n = 0; n < 4; n++) {
    int col = gn0 + n * 16 + (l & 15);
    float bv = bias[col];
    #pragma unroll
    for (int m = 0; m < 4; m++) {
      int rowb = gm0 + m * 16 + ((l >> 4) << 2);
      #pragma unroll
      for (int j = 0; j < 4; j++)
        out[(size_t)(rowb + j) * DIMSZ + col] = acc[m][n][j] + bv;
    }
  }
}

// ---------------- Flash attention ----------------
// grid 512: bid = bh*16 + qtile. 4 waves, each owns 32 q-rows. KT=64.
__global__ __launch_bounds__(256) void k_attn(
    const f16* __restrict__ qb, const f16* __restrict__ kb,
    const f16* __restrict__ vb, f16* __restrict__ ctx) {
  __shared__ __align__(16) f16 Ks[64 * 64];
  __shared__ __align__(16) f16 Vs[64 * 64];   // V^T tile: [d][key]
  __shared__ __align__(16) f16 Ps[4][32 * 64];
  int tid = threadIdx.x, l = tid & 63, w = tid >> 6;
  int bid = blockIdx.x;
  int qtile = bid & 15, bh = bid >> 4;
  const f16* Qg = qb + ((size_t)bh * SEQ + qtile * 128) * 64;
  const f16* Kg = kb + (size_t)bh * SEQ * 64;
  const f16* Vg = vb + (size_t)bh * 64 * SEQ;

  f16x8 qf[2][2];
  #pragma unroll
  for (int mi = 0; mi < 2; mi++)
    #pragma unroll
    for (int kk = 0; kk < 2; kk++)
      qf[mi][kk] = *(const f16x8*)(Qg + (size_t)(w * 32 + mi * 16 + (l & 15)) * 64
                                   + kk * 32 + (l >> 4) * 8);

  f32x4 o[2][4] = {};
  float mrun[2][4], lrun[2][4];
  #pragma unroll
  for (int mi = 0; mi < 2; mi++)
    #pragma unroll
    for (int j = 0; j < 4; j++) { mrun[mi][j] = -INFINITY; lrun[mi][j] = 0.f; }

  const float SC = 0.125f * 1.44269504f;  // scale folded into exp2

  for (int t = 0; t < 32; t++) {
    __syncthreads();
    const f16* Kt = Kg + (size_t)t * 64 * 64;   // contiguous tile
    #pragma unroll
    for (int i = 0; i < 2; i++) {
      int base = i * 256 + w * 64, chunk = base + l;
      int row = chunk >> 3, c = chunk & 7, sc = c ^ (row & 7);
      gload_lds16(Kt + row * 64 + sc * 8, &Ks[base * 8]);
    }
    const f16* Vt = Vg + (size_t)t * 64;        // rows (=d) strided by SEQ
    #pragma unroll
    for (int i = 0; i < 2; i++) {
      int base = i * 256 + w * 64, chunk = base + l;
      int d = chunk >> 3, c = chunk & 7, sc = c ^ (d & 7);
      gload_lds16(Vt + (size_t)d * SEQ + sc * 8, &Vs[base * 8]);
    }
    __syncthreads();

    // S = Q K^T (unscaled)
    f32x4 s[2][4] = {};
    f16x8 kf[4][2];
    #pragma unroll
    for (int n = 0; n < 4; n++)
      #pragma unroll
      for (int kk = 0; kk < 2; kk++) {
        int row = n * 16 + (l & 15);
        int pc = (kk * 4 + (l >> 4)) ^ (row & 7);
        kf[n][kk] = *(const f16x8*)&Ks[row * 64 + pc * 8];
      }
    #pragma unroll
    for (int mi = 0; mi < 2; mi++)
      #pragma unroll
      for (int n = 0; n < 4; n++)
        #pragma unroll
        for (int kk = 0; kk < 2; kk++)
          s[mi][n] = __builtin_amdgcn_mfma_f32_16x16x32_f16(qf[mi][kk], kf[n][kk],
                                                            s[mi][n], 0, 0, 0);

    // online softmax (rows live in 16-lane groups; reduce over l&15)
    #pragma unroll
    for (int mi = 0; mi < 2; mi++) {
      #pragma unroll
      for (int j = 0; j < 4; j++) {
        float tm = fmaxf(fmaxf(s[mi][0][j], s[mi][1][j]),
                         fmaxf(s[mi][2][j], s[mi][3][j]));
        tm = fmaxf(tm, __shfl_xor(tm, 1));
        tm = fmaxf(tm, __shfl_xor(tm, 2));
        tm = fmaxf(tm, __shfl_xor(tm, 4));
        tm = fmaxf(tm, __shfl_xor(tm, 8));
        float mnew = fmaxf(mrun[mi][j], tm);
        float corr = __builtin_amdgcn_exp2f((mrun[mi][j] - mnew) * SC);
        mrun[mi][j] = mnew;
        float ts = 0.f;
        #pragma unroll
        for (int n = 0; n < 4; n++) {
          float p = __builtin_amdgcn_exp2f((s[mi][n][j] - mnew) * SC);
          s[mi][n][j] = p;
          ts += p;
        }
        ts += __shfl_xor(ts, 1);
        ts += __shfl_xor(ts, 2);
        ts += __shfl_xor(ts, 4);
        ts += __shfl_xor(ts, 8);
        lrun[mi][j] = lrun[mi][j] * corr + ts;
        #pragma unroll
        for (int nd = 0; nd < 4; nd++) o[mi][nd][j] *= corr;
      }
    }

    // P -> LDS (wave-private region, XOR-swizzled like all tiles)
    #pragma unroll
    for (int mi = 0; mi < 2; mi++)
      #pragma unroll
      for (int n = 0; n < 4; n++)
        #pragma unroll
        for (int j = 0; j < 4; j++) {
          int r = mi * 16 + ((l >> 4) << 2) + j;
          int colc = n * 16 + (l & 15);
          int pcc = (colc >> 3) ^ (r & 7);
          Ps[w][r * 64 + pcc * 8 + (colc & 7)] = (f16)s[mi][n][j];
        }
    asm volatile("s_waitcnt lgkmcnt(0)" ::: "memory");

    // O += P V
    f16x8 pf[2][2], vf[4][2];
    #pragma unroll
    for (int mi = 0; mi < 2; mi++)
      #pragma unroll
      for (int kk = 0; kk < 2; kk++) {
        int r = mi * 16 + (l & 15);
        int pc = (kk * 4 + (l >> 4)) ^ (r & 7);
        pf[mi][kk] = *(const f16x8*)&Ps[w][r * 64 + pc * 8];
      }
    #pragma unroll
    for (int nd = 0; nd < 4; nd++)
      #pragma unroll
      for (int kk = 0; kk < 2; kk++) {
        int d = nd * 16 + (l & 15);
        int pc = (kk * 4 + (l >> 4)) ^ (d & 7);
        vf[nd][kk] = *(const f16x8*)&Vs[d * 64 + pc * 8];
      }
    #pragma unroll
    for (int mi = 0; mi < 2; mi++)
      #pragma unroll
      for (int nd = 0; nd < 4; nd++)
        #pragma unroll
        for (int kk = 0; kk < 2; kk++)
          o[mi][nd] = __builtin_amdgcn_mfma_f32_16x16x32_f16(pf[mi][kk], vf[nd][kk],
                                                             o[mi][nd], 0, 0, 0);
  }

  // normalize + write ctx [B*N][1024] fp16
  int b = bh >> 4, h = bh & 15;
  #pragma unroll
  for (int mi = 0; mi < 2; mi++)
    #pragma unroll
    for (int j = 0; j < 4; j++) {
      float inv = 1.0f / lrun[mi][j];
      int q = qtile * 128 + w * 32 + mi * 16 + ((l >> 4) << 2) + j;
      #pragma unroll
      for (int nd = 0; nd < 4; nd++) {
        int d = nd * 16 + (l & 15);
        ctx[((size_t)(b * SEQ + q)) * DIMSZ + h * 64 + d] = (f16)(o[mi][nd][j] * inv);
      }
    }
}

extern "C" void kernel_launch(void* const* d_in, const int* in_sizes, int n_in,
                              void* d_out, int out_size, void* d_ws, size_t ws_size,
                              hipStream_t stream) {
  const float* x    = (const float*)d_in[0];
  const float* Wqkv = (const float*)d_in[1];
  const float* bqkv = (const float*)d_in[2];
  const float* Wout = (const float*)d_in[3];
  const float* bout = (const float*)d_in[4];
  float* out = (float*)d_out;
  char* ws = (char*)d_ws;

  // workspace layout (bytes); ctx reuses the xh region (xh dead after GEMM1)
  f16* xh    = (f16*)(ws);                  // 8,388,608
  f16* ctx   = xh;
  f16* wqkvt = (f16*)(ws + 8388608);        // 6,291,456
  f16* woutt = (f16*)(ws + 14680064);       // 2,097,152
  f16* qbuf  = (f16*)(ws + 16777216);       // 8,388,608
  f16* kbuf  = (f16*)(ws + 25165824);       // 8,388,608
  f16* vbuf  = (f16*)(ws + 33554432);       // 8,388,608  (end 41,943,040)

  k_cvt_x<<<4096, 256, 0, stream>>>(x, xh);
  k_tcvt<<<dim3(48, 16), 256, 0, stream>>>(Wqkv, wqkvt, DIMSZ, 3 * DIMSZ);
  k_tcvt<<<dim3(16, 16), 256, 0, stream>>>(Wout, woutt, DIMSZ, DIMSZ);
  k_gemm_qkv<<<dim3(24, 32), 256, 0, stream>>>(xh, wqkvt, bqkv, qbuf, kbuf, vbuf);
  k_attn<<<512, 256, 0, stream>>>(qbuf, kbuf, vbuf, ctx);
  k_gemm_out<<<dim3(8, 32), 256, 0, stream>>>(ctx, woutt, bout, out);
}

// Round 3
// 206.092 us; speedup vs baseline: 1.3220x; 1.3220x over previous
//
#include <hip/hip_runtime.h>
#include <hip/hip_bf16.h>
#include <hip/hip_fp16.h>

// Problem constants
#define DIMSZ 1024
#define HEADS 16
#define HD 64
#define BATCH 2
#define SEQ 2048
#define MROWS (BATCH*SEQ)   // 4096

typedef _Float16 f16;
typedef _Float16 f16x8 __attribute__((ext_vector_type(8)));
typedef float f32x4 __attribute__((ext_vector_type(4)));

__device__ __forceinline__ void gload_lds16(const void* g, void* l) {
  // 16B direct global->LDS: dest = wave-uniform base + lane*16
  __builtin_amdgcn_global_load_lds(
      (const __attribute__((address_space(1))) unsigned int*)g,
      (__attribute__((address_space(3))) unsigned int*)l, 16, 0, 0);
}

// ---------------- fp32 -> fp16 elementwise (x) ----------------
__global__ __launch_bounds__(256) void k_cvt_x(const float* __restrict__ in,
                                               f16* __restrict__ out) {
  int i = blockIdx.x * 256 + threadIdx.x;   // 4096*1024/4 elems of float4
  float4 v = ((const float4*)in)[i];
  union { f16 h[4]; uint2 u; } p;
  p.h[0] = (f16)v.x; p.h[1] = (f16)v.y; p.h[2] = (f16)v.z; p.h[3] = (f16)v.w;
  ((uint2*)out)[i] = p.u;
}

// ---------------- fp32 [R][C] -> fp16 [C][R] transpose ----------------
__global__ __launch_bounds__(256) void k_tcvt(const float* __restrict__ in,
                                              f16* __restrict__ out,
                                              int R, int C) {
  __shared__ f16 t[64][66];  // +2 pad: conflict-free col reads
  int c0 = blockIdx.x * 64, r0 = blockIdx.y * 64;
  int tid = threadIdx.x;
  int cc = tid & 63;
  #pragma unroll
  for (int p = 0; p < 16; p++) {
    int r = p * 4 + (tid >> 6);
    t[r][cc] = (f16)in[(size_t)(r0 + r) * C + c0 + cc];
  }
  __syncthreads();
  int rr = tid & 63;
  #pragma unroll
  for (int p = 0; p < 16; p++) {
    int c = p * 4 + (tid >> 6);
    out[(size_t)(c0 + c) * R + r0 + rr] = t[rr][c];
  }
}

// ---------------- GEMM core (shared shape): C[128x128] tile, BK=64 ----------
// A: [M][1024] fp16 row-major, Bt: [N][1024] fp16 row-major (i.e. B transposed)
// 256 threads = 4 waves in 2x2, each wave 64x64 (4x4 frags of 16x16x32_f16)
#define GEMM_CORE(Aptr, Bptr)                                                  \
  __shared__ __align__(16) f16 As[128 * 64];                                   \
  __shared__ __align__(16) f16 Bs[128 * 64];                                   \
  const int K = 1024;                                                          \
  int tid = threadIdx.x, l = tid & 63, w = tid >> 6;                           \
  int bm = blockIdx.y, bn = blockIdx.x;                                        \
  int wr = (w >> 1) * 64, wc = (w & 1) * 64;                                   \
  const f16* Ag = (Aptr) + (size_t)bm * 128 * K;                               \
  const f16* Bg = (Bptr) + (size_t)bn * 128 * K;                               \
  f32x4 acc[4][4] = {};                                                        \
  for (int kt = 0; kt < K; kt += 64) {                                         \
    __syncthreads();                                                           \
    _Pragma("unroll")                                                          \
    for (int i = 0; i < 4; i++) {                                              \
      int base = i * 256 + w * 64;                                             \
      int chunk = base + l;                                                    \
      int row = chunk >> 3, c = chunk & 7, sc = c ^ (row & 7);                 \
      gload_lds16(Ag + (size_t)row * K + kt + sc * 8, &As[base * 8]);          \
    }                                                                          \
    _Pragma("unroll")                                                          \
    for (int i = 0; i < 4; i++) {                                              \
      int base = i * 256 + w * 64;                                             \
      int chunk = base + l;                                                    \
      int row = chunk >> 3, c = chunk & 7, sc = c ^ (row & 7);                 \
      gload_lds16(Bg + (size_t)row * K + kt + sc * 8, &Bs[base * 8]);          \
    }                                                                          \
    __syncthreads();                                                           \
    f16x8 af[4][2], bf[4][2];                                                  \
    _Pragma("unroll")                                                          \
    for (int m = 0; m < 4; m++)                                                \
      _Pragma("unroll")                                                        \
      for (int kk = 0; kk < 2; kk++) {                                         \
        int row = wr + m * 16 + (l & 15);                                      \
        int pc = (kk * 4 + (l >> 4)) ^ (row & 7);                              \
        af[m][kk] = *(const f16x8*)&As[row * 64 + pc * 8];                     \
      }                                                                        \
    _Pragma("unroll")                                                          \
    for (int n = 0; n < 4; n++)                                                \
      _Pragma("unroll")                                                        \
      for (int kk = 0; kk < 2; kk++) {                                         \
        int row = wc + n * 16 + (l & 15);                                      \
        int pc = (kk * 4 + (l >> 4)) ^ (row & 7);                              \
        bf[n][kk] = *(const f16x8*)&Bs[row * 64 + pc * 8];                     \
      }                                                                        \
    _Pragma("unroll")                                                          \
    for (int m = 0; m < 4; m++)                                                \
      _Pragma("unroll")                                                        \
      for (int n = 0; n < 4; n++)                                              \
        _Pragma("unroll")                                                      \
        for (int kk = 0; kk < 2; kk++)                                         \
          acc[m][n] = __builtin_amdgcn_mfma_f32_16x16x32_f16(af[m][kk],        \
                          bf[n][kk], acc[m][n], 0, 0, 0);                      \
  }

// QKV projection: writes Q,K as [B*H][SEQ][64] fp16, V as [B*H][64][SEQ] fp16
__global__ __launch_bounds__(256) void k_gemm_qkv(
    const f16* __restrict__ A, const f16* __restrict__ Bt,
    const float* __restrict__ bias,
    f16* __restrict__ qb, f16* __restrict__ kb, f16* __restrict__ vb) {
  GEMM_CORE(A, Bt)
  int gm0 = bm * 128 + wr;
  int gn0 = bn * 128 + wc;
  #pragma unroll
  for (int n = 0; n < 4; n++) {
    int col = gn0 + n * 16 + (l & 15);
    float bv = bias[col];
    int which = col >> 10, rest = col & 1023, h = rest >> 6, d = rest & 63;
    #pragma unroll
    for (int m = 0; m < 4; m++) {
      int rowb = gm0 + m * 16 + ((l >> 4) << 2);
      int b = rowb >> 11, nn = rowb & 2047;
      if (which == 2) {
        union { f16 h[4]; uint2 u; } pk;
        #pragma unroll
        for (int j = 0; j < 4; j++) pk.h[j] = (f16)(acc[m][n][j] + bv);
        *(uint2*)(vb + ((size_t)(b * HEADS + h) * 64 + d) * SEQ + nn) = pk.u;
      } else {
        f16* dst = (which ? kb : qb) + ((size_t)(b * HEADS + h) * SEQ + nn) * 64 + d;
        #pragma unroll
        for (int j = 0; j < 4; j++) dst[(size_t)j * 64] = (f16)(acc[m][n][j] + bv);
      }
    }
  }
}

// Output projection: ctx[4096][1024] fp16 @ Wout^T -> fp32 out + bias
__global__ __launch_bounds__(256) void k_gemm_out(
    const f16* __restrict__ A, const f16* __restrict__ Bt,
    const float* __restrict__ bias, float* __restrict__ out) {
  GEMM_CORE(A, Bt)
  int gm0 = bm * 128 + wr;
  int gn0 = bn * 128 + wc;
  #pragma unroll
  for (int n = 0; n < 4; n++) {
    int col = gn0 + n * 16 + (l & 15);
    float bv = bias[col];
    #pragma unroll
    for (int m = 0; m < 4; m++) {
      int rowb = gm0 + m * 16 + ((l >> 4) << 2);
      #pragma unroll
      for (int j = 0; j < 4; j++)
        out[(size_t)(rowb + j) * DIMSZ + col] = acc[m][n][j] + bv;
    }
  }
}

// ---------------- Flash attention (v2) ----------------
// 512 threads = 8 waves, each wave owns 16 q-rows (block = 128 q-rows).
// grid 512: bid = bh*16 + qtile. KV-tile = 64 keys, double-buffered with
// prefetch-before-compute (one barrier per tile).
// Swapped QK^T: S^T = mfma(K, Q) -> softmax reduce is in-lane + 2 shfls,
// P^T stored once per wave (4x 8B swizzled LDS writes), PV computes
// O^T = V^T * P^T.
__global__ __launch_bounds__(512) void k_attn(
    const f16* __restrict__ qb, const f16* __restrict__ kb,
    const f16* __restrict__ vb, f16* __restrict__ ctx) {
  __shared__ __align__(16) f16 Ks[2][64 * 64];
  __shared__ __align__(16) f16 Vs[2][64 * 64];   // V^T tile: [d][key]
  __shared__ __align__(16) f16 Pl[8][16 * 64];   // per-wave P[q][kv], swizzled
  int tid = threadIdx.x, l = tid & 63, w = tid >> 6;
  int g = l >> 4, q = l & 15;
  int bid = blockIdx.x;
  int qtile = bid & 15, bh = bid >> 4;
  const f16* Qg = qb + ((size_t)bh * SEQ + qtile * 128 + w * 16) * 64;
  const f16* Kg = kb + (size_t)bh * SEQ * 64;
  const f16* Vg = vb + (size_t)bh * 64 * SEQ;

  // Q fragments (B-operand): lane holds Q[q0+q][kk*32 + g*8 + j]
  f16x8 qf[2];
  #pragma unroll
  for (int kk = 0; kk < 2; kk++)
    qf[kk] = *(const f16x8*)(Qg + (size_t)q * 64 + kk * 32 + g * 8);

  f32x4 o[4] = {};
  float mrun = -INFINITY, lrun = 0.f;
  const float SC = 0.125f * 1.44269504f;  // 1/sqrt(64) folded into exp2

  // staging: 512 threads x 16B = one full 64x64 f16 tile each for K and V
  int srow = tid >> 3, scc = tid & 7;
  int ssc = scc ^ (srow & 7);
  const f16* Ksrc = Kg + (size_t)srow * 64 + ssc * 8;   // +t*4096
  const f16* Vsrc = Vg + (size_t)srow * SEQ + ssc * 8;  // +t*64

#define ATTN_STAGE(t, b) do {                                   \
    gload_lds16(Ksrc + (size_t)(t) * 4096, &Ks[b][w * 512]);    \
    gload_lds16(Vsrc + (size_t)(t) * 64,   &Vs[b][w * 512]);    \
  } while (0)

  ATTN_STAGE(0, 0);
  __syncthreads();

  for (int t = 0; t < 32; t++) {
    int cur = t & 1;
    if (t < 31) ATTN_STAGE(t + 1, cur ^ 1);   // prefetch hides HBM latency

    // S^T = K * Q  (A = K rows = kv, B = Q cols = q)
    f16x8 kf[4][2];
    #pragma unroll
    for (int n = 0; n < 4; n++)
      #pragma unroll
      for (int kk = 0; kk < 2; kk++) {
        int row = n * 16 + q;
        int pc = (kk * 4 + g) ^ (row & 7);
        kf[n][kk] = *(const f16x8*)&Ks[cur][row * 64 + pc * 8];
      }
    f32x4 s[4] = {};
    #pragma unroll
    for (int n = 0; n < 4; n++)
      #pragma unroll
      for (int kk = 0; kk < 2; kk++)
        s[n] = __builtin_amdgcn_mfma_f32_16x16x32_f16(kf[n][kk], qf[kk], s[n],
                                                      0, 0, 0);
    // lane holds S^T[kv = n*16 + g*4 + j][q]; online softmax per q (in-lane
    // over 16 values, then shfl over the 4 lane-groups)
    float tm = -INFINITY;
    #pragma unroll
    for (int n = 0; n < 4; n++)
      #pragma unroll
      for (int j = 0; j < 4; j++) tm = fmaxf(tm, s[n][j]);
    tm = fmaxf(tm, __shfl_xor(tm, 16));
    tm = fmaxf(tm, __shfl_xor(tm, 32));
    float mnew = fmaxf(mrun, tm);
    float a = mnew * SC;
    float corr = __builtin_amdgcn_exp2f(mrun * SC - a);
    float ts = 0.f;
    #pragma unroll
    for (int n = 0; n < 4; n++)
      #pragma unroll
      for (int j = 0; j < 4; j++) {
        float pv = __builtin_amdgcn_exp2f(s[n][j] * SC - a);
        s[n][j] = pv;
        ts += pv;
      }
    ts += __shfl_xor(ts, 16);
    ts += __shfl_xor(ts, 32);
    lrun = lrun * corr + ts;
    mrun = mnew;
    #pragma unroll
    for (int nd = 0; nd < 4; nd++) o[nd] *= corr;

    // P^T -> wave-private LDS as P[q][kv], chunk-swizzled like Ks
    #pragma unroll
    for (int n = 0; n < 4; n++) {
      union { f16 h4[4]; uint2 u; } pk;
      #pragma unroll
      for (int j = 0; j < 4; j++) pk.h4[j] = (f16)s[n][j];
      int c = 2 * n + (g >> 1);
      *(uint2*)&Pl[w][q * 64 + ((c ^ (q & 7)) * 8) + (g & 1) * 4] = pk.u;
    }
    asm volatile("s_waitcnt lgkmcnt(0)" ::: "memory");
    __builtin_amdgcn_sched_barrier(0);

    // O^T += V^T * P^T   (A = V^T rows = d, B = P^T cols = q)
    f16x8 pf[2], vf[4][2];
    #pragma unroll
    for (int kk = 0; kk < 2; kk++) {
      int c = kk * 4 + g;
      pf[kk] = *(const f16x8*)&Pl[w][q * 64 + ((c ^ (q & 7)) * 8)];
    }
    #pragma unroll
    for (int nd = 0; nd < 4; nd++)
      #pragma unroll
      for (int kk = 0; kk < 2; kk++) {
        int row = nd * 16 + q;
        int pc = (kk * 4 + g) ^ (row & 7);
        vf[nd][kk] = *(const f16x8*)&Vs[cur][row * 64 + pc * 8];
      }
    #pragma unroll
    for (int nd = 0; nd < 4; nd++)
      #pragma unroll
      for (int kk = 0; kk < 2; kk++)
        o[nd] = __builtin_amdgcn_mfma_f32_16x16x32_f16(vf[nd][kk], pf[kk],
                                                       o[nd], 0, 0, 0);
    __syncthreads();  // implicit vmcnt drain completes the prefetch
  }

  // O^T[d][q]: lane holds d = nd*16 + g*4 + j for its q -> 8B packed writes
  float inv = 1.0f / lrun;
  int b = bh >> 4, h = bh & 15;
  size_t rowoff = ((size_t)(b * SEQ + qtile * 128 + w * 16 + q)) * DIMSZ + h * 64;
  #pragma unroll
  for (int nd = 0; nd < 4; nd++) {
    union { f16 h4[4]; uint2 u; } pk;
    #pragma unroll
    for (int j = 0; j < 4; j++) pk.h4[j] = (f16)(o[nd][j] * inv);
    *(uint2*)(ctx + rowoff + nd * 16 + g * 4) = pk.u;
  }
#undef ATTN_STAGE
}

extern "C" void kernel_launch(void* const* d_in, const int* in_sizes, int n_in,
                              void* d_out, int out_size, void* d_ws, size_t ws_size,
                              hipStream_t stream) {
  const float* x    = (const float*)d_in[0];
  const float* Wqkv = (const float*)d_in[1];
  const float* bqkv = (const float*)d_in[2];
  const float* Wout = (const float*)d_in[3];
  const float* bout = (const float*)d_in[4];
  float* out = (float*)d_out;
  char* ws = (char*)d_ws;

  // workspace layout (bytes); ctx reuses the xh region (xh dead after GEMM1)
  f16* xh    = (f16*)(ws);                  // 8,388,608
  f16* ctx   = xh;
  f16* wqkvt = (f16*)(ws + 8388608);        // 6,291,456
  f16* woutt = (f16*)(ws + 14680064);       // 2,097,152
  f16* qbuf  = (f16*)(ws + 16777216);       // 8,388,608
  f16* kbuf  = (f16*)(ws + 25165824);       // 8,388,608
  f16* vbuf  = (f16*)(ws + 33554432);       // 8,388,608  (end 41,943,040)

  k_cvt_x<<<4096, 256, 0, stream>>>(x, xh);
  k_tcvt<<<dim3(48, 16), 256, 0, stream>>>(Wqkv, wqkvt, DIMSZ, 3 * DIMSZ);
  k_tcvt<<<dim3(16, 16), 256, 0, stream>>>(Wout, woutt, DIMSZ, DIMSZ);
  k_gemm_qkv<<<dim3(24, 32), 256, 0, stream>>>(xh, wqkvt, bqkv, qbuf, kbuf, vbuf);
  k_attn<<<512, 512, 0, stream>>>(qbuf, kbuf, vbuf, ctx);
  k_gemm_out<<<dim3(8, 32), 256, 0, stream>>>(ctx, woutt, bout, out);
}